// Round 1
// baseline (279.000 us; speedup 1.0000x reference)
//
#include <hip/hip_runtime.h>

typedef __bf16 bf16;
typedef bf16 bf16x8 __attribute__((ext_vector_type(8)));
typedef bf16 bf16x4 __attribute__((ext_vector_type(4)));
typedef float f32x4 __attribute__((ext_vector_type(4)));

#define MFMA16(a, b, c) __builtin_amdgcn_mfma_f32_16x16x32_bf16(a, b, c, 0, 0, 0)

// ---------------- prep kernels ----------------

// fp32 -> bf16, 4 elements/thread
__global__ void k_cvt(const float* __restrict__ in, bf16* __restrict__ out) {
  int i = (blockIdx.x * 256 + threadIdx.x) * 4;
  float4 v = *(const float4*)(in + i);
  bf16x4 o;
  o[0] = (bf16)v.x; o[1] = (bf16)v.y; o[2] = (bf16)v.z; o[3] = (bf16)v.w;
  *(bf16x4*)(out + i) = o;
}

// transpose fp32 [256][Cc] -> bf16 [Cc][256]
__global__ void k_tr256(const float* __restrict__ in, bf16* __restrict__ out, int Cc) {
  int id = blockIdx.x * 256 + threadIdx.x;   // id = c*256 + r (output-linear)
  int c = id >> 8, r = id & 255;
  out[id] = (bf16)in[r * Cc + c];
}

// sr_w [o][i][p] (p = kh*4+kw, 16) -> srwT [o][p*256 + i]  bf16
__global__ void k_srw(const float* __restrict__ in, bf16* __restrict__ out) {
  int id = blockIdx.x * 256 + threadIdx.x;   // input-linear: o*4096 + i*16 + p
  int o = id >> 12, rem = id & 4095;
  int i = rem >> 4, p = rem & 15;
  out[(o << 12) + (p << 8) + i] = (bf16)in[id];
}

// ---------------- generic MFMA GEMM ----------------
// C[M][N] = A[M][K] @ Bt[N][K]^T   (bf16 inputs, fp32 accum)
// AMODE 0: A row-major [M][K]
// AMODE 1: conv im2col gather from x_bf [B*4096][256]; K index = p*256 + i
// EMODE 0: bf16 store [M][N]
// EMODE 1: fp32 store + bias (conv out)
// EMODE 2: KV scatter: col<256 -> Kbuf[(b*4+h)*256+key][d]; col>=256 -> Vbuf (+32*256*64)
// EMODE 3: fp32 store + bias (final output)
template <int AMODE, int EMODE>
__global__ __launch_bounds__(256, 2) void k_gemm(
    const bf16* __restrict__ A, const bf16* __restrict__ Bt,
    void* __restrict__ Cout, const float* __restrict__ bias,
    int M, int N, int K) {
  constexpr int LDT = 72;  // 64 + 8 pad (16B-odd stride -> conflict-free b128)
  __shared__ alignas(16) bf16 As[64 * LDT];
  __shared__ alignas(16) bf16 Bs[64 * LDT];
  int tid = threadIdx.x;
  int m0 = blockIdx.x * 64, n0 = blockIdx.y * 64;
  int wave = tid >> 6, lane = tid & 63;
  int quad = lane >> 4, l16 = lane & 15;

  f32x4 acc[4];
#pragma unroll
  for (int i = 0; i < 4; i++) acc[i] = (f32x4){0.f, 0.f, 0.f, 0.f};

  for (int k0 = 0; k0 < K; k0 += 64) {
#pragma unroll
    for (int t = 0; t < 2; t++) {
      int c = tid + t * 256;
      int row = c >> 3, c8 = (c & 7) * 8;
      const bf16* asrc;
      if constexpr (AMODE == 0) {
        asrc = A + (size_t)(m0 + row) * K + k0 + c8;
      } else {
        int m = m0 + row;
        int b = m >> 8, tt = m & 255;
        int oh = tt >> 4, ow = tt & 15;
        int p = k0 >> 8;            // patch position (BK=64 never straddles p)
        int kh = p >> 2, kw = p & 3;
        int tok = (oh * 4 + kh) * 64 + ow * 4 + kw;
        asrc = A + ((size_t)(b * 4096 + tok) << 8) + (k0 & 255) + c8;
      }
      *(bf16x8*)&As[row * LDT + c8] = *(const bf16x8*)asrc;
      *(bf16x8*)&Bs[row * LDT + c8] =
          *(const bf16x8*)(Bt + (size_t)(n0 + row) * K + k0 + c8);
    }
    __syncthreads();
#pragma unroll
    for (int kk = 0; kk < 64; kk += 32) {
      bf16x8 af = *(const bf16x8*)&As[(wave * 16 + l16) * LDT + kk + quad * 8];
#pragma unroll
      for (int nt = 0; nt < 4; nt++) {
        bf16x8 bfr = *(const bf16x8*)&Bs[(nt * 16 + l16) * LDT + kk + quad * 8];
        acc[nt] = MFMA16(af, bfr, acc[nt]);
      }
    }
    __syncthreads();
  }

  // epilogue: D[row=quad*4+r][col=l16] per n-tile
  int rbase = m0 + wave * 16 + quad * 4;
#pragma unroll
  for (int nt = 0; nt < 4; nt++) {
    int col = n0 + nt * 16 + l16;
#pragma unroll
    for (int r = 0; r < 4; r++) {
      float v = acc[nt][r];
      int row = rbase + r;
      if constexpr (EMODE == 0) {
        ((bf16*)Cout)[(size_t)row * N + col] = (bf16)v;
      } else if constexpr (EMODE == 1) {
        ((float*)Cout)[(size_t)row * N + col] = v + bias[col];
      } else if constexpr (EMODE == 2) {
        int b = row >> 8, key = row & 255;
        int isv = col >> 8, c2 = col & 255;
        int hh = c2 >> 6, d = c2 & 63;
        bf16* dst = (bf16*)Cout + ((size_t)isv * 32 * 256 * 64);
        dst[(((size_t)(b * 4 + hh)) * 256 + key) * 64 + d] = (bf16)v;
      } else {
        ((float*)Cout)[(size_t)row * N + col] = v + bias[col];
      }
    }
  }
}

// ---------------- LayerNorm (conv out fp32 -> bf16) ----------------
__global__ void k_ln(const float* __restrict__ xin, const float* __restrict__ g,
                     const float* __restrict__ bb, bf16* __restrict__ out) {
  int row = blockIdx.x * 4 + (threadIdx.x >> 6);
  int lane = threadIdx.x & 63;
  float4 v = *(const float4*)&xin[(size_t)row * 256 + lane * 4];
  float s = v.x + v.y + v.z + v.w;
#pragma unroll
  for (int i = 1; i < 64; i <<= 1) s += __shfl_xor(s, i, 64);
  float mu = s * (1.f / 256.f);
  float d0 = v.x - mu, d1 = v.y - mu, d2 = v.z - mu, d3 = v.w - mu;
  float q = d0 * d0 + d1 * d1 + d2 * d2 + d3 * d3;
#pragma unroll
  for (int i = 1; i < 64; i <<= 1) q += __shfl_xor(q, i, 64);
  float rs = rsqrtf(q * (1.f / 256.f) + 1e-5f);
  int c = lane * 4;
  bf16x4 o;
  o[0] = (bf16)(d0 * rs * g[c + 0] + bb[c + 0]);
  o[1] = (bf16)(d1 * rs * g[c + 1] + bb[c + 1]);
  o[2] = (bf16)(d2 * rs * g[c + 2] + bb[c + 2]);
  o[3] = (bf16)(d3 * rs * g[c + 3] + bb[c + 3]);
  *(bf16x4*)&out[(size_t)row * 256 + c] = o;
}

// ---------------- attention ----------------
// grid (32 bh, 64 qtiles), block 256 (4 waves); each block: 64 q x 256 keys
__global__ __launch_bounds__(256, 2) void k_attn(
    const bf16* __restrict__ Q,   // [B*4096][256], col = h*64+d
    const bf16* __restrict__ Kb,  // [32][256][64]
    const bf16* __restrict__ Vb,  // [32][256][64]
    bf16* __restrict__ O) {       // [B*4096][256]
  int bh = blockIdx.x, qt = blockIdx.y;
  int b = bh >> 2, h = bh & 3;
  int tid = threadIdx.x, wave = tid >> 6, lane = tid & 63;
  int quad = lane >> 4, l16 = lane & 15;

  // Qs[64][72] | Ks[256][72] | Vt[64][264];  Ps[64][264] aliases Qs+Ks
  __shared__ alignas(16) bf16 smem[64 * 72 + 256 * 72 + 64 * 264];
  bf16* Qs = smem;
  bf16* Ks = smem + 64 * 72;
  bf16* Vt = smem + 64 * 72 + 256 * 72;
  bf16* Ps = smem;

  // stage Q tile
#pragma unroll
  for (int t = 0; t < 2; t++) {
    int c = tid + t * 256;
    int row = c >> 3, c8 = (c & 7) * 8;
    *(bf16x8*)&Qs[row * 72 + c8] =
        *(const bf16x8*)&Q[((size_t)(b * 4096 + qt * 64 + row) << 8) + h * 64 + c8];
  }
  // stage K
  const bf16* Kbh = Kb + (size_t)bh * 256 * 64;
#pragma unroll
  for (int t = 0; t < 8; t++) {
    int c = tid + t * 256;
    int row = c >> 3, c8 = (c & 7) * 8;
    *(bf16x8*)&Ks[row * 72 + c8] = *(const bf16x8*)&Kbh[row * 64 + c8];
  }
  // stage V transposed: Vt[d][key]
  {
    const bf16* Vbh = Vb + (size_t)bh * 256 * 64;
    int key = tid;
#pragma unroll
    for (int t = 0; t < 8; t++) {
      bf16x8 v = *(const bf16x8*)&Vbh[key * 64 + t * 8];
#pragma unroll
      for (int j = 0; j < 8; j++) Vt[(t * 8 + j) * 264 + key] = v[j];
    }
  }
  __syncthreads();

  // S = Q K^T : wave handles 16 q-rows x all 256 keys
  f32x4 s[16];
#pragma unroll
  for (int i = 0; i < 16; i++) s[i] = (f32x4){0.f, 0.f, 0.f, 0.f};
  bf16x8 aq0 = *(const bf16x8*)&Qs[(wave * 16 + l16) * 72 + 0 + quad * 8];
  bf16x8 aq1 = *(const bf16x8*)&Qs[(wave * 16 + l16) * 72 + 32 + quad * 8];
#pragma unroll
  for (int nt = 0; nt < 16; nt++) {
    bf16x8 b0 = *(const bf16x8*)&Ks[(nt * 16 + l16) * 72 + 0 + quad * 8];
    bf16x8 b1 = *(const bf16x8*)&Ks[(nt * 16 + l16) * 72 + 32 + quad * 8];
    s[nt] = MFMA16(aq0, b0, s[nt]);
    s[nt] = MFMA16(aq1, b1, s[nt]);
  }

  // softmax over 256 keys; lane holds rows quad*4+r, col l16 of each 16-tile
  const float scale = 0.125f;
#pragma unroll
  for (int r = 0; r < 4; r++) {
    float m = -1e30f;
#pragma unroll
    for (int nt = 0; nt < 16; nt++) m = fmaxf(m, s[nt][r]);
#pragma unroll
    for (int i = 1; i < 16; i <<= 1) m = fmaxf(m, __shfl_xor(m, i, 64));
    float sum = 0.f;
#pragma unroll
    for (int nt = 0; nt < 16; nt++) {
      float e = __expf((s[nt][r] - m) * scale);
      s[nt][r] = e;
      sum += e;
    }
#pragma unroll
    for (int i = 1; i < 16; i <<= 1) sum += __shfl_xor(sum, i, 64);
    float inv = 1.f / sum;
#pragma unroll
    for (int nt = 0; nt < 16; nt++) s[nt][r] *= inv;
  }

  __syncthreads();  // done reading Qs/Ks; Ps aliases them
  // write P (C-layout -> LDS row-major)
#pragma unroll
  for (int nt = 0; nt < 16; nt++)
#pragma unroll
    for (int r = 0; r < 4; r++)
      Ps[(wave * 16 + quad * 4 + r) * 264 + nt * 16 + l16] = (bf16)s[nt][r];
  __syncthreads();

  // O = P V : A = Ps [64 q][256 key], B = V[key][d] read via Vt[d][key]
  f32x4 o[4];
#pragma unroll
  for (int i = 0; i < 4; i++) o[i] = (f32x4){0.f, 0.f, 0.f, 0.f};
#pragma unroll
  for (int k0 = 0; k0 < 256; k0 += 32) {
    bf16x8 ap = *(const bf16x8*)&Ps[(wave * 16 + l16) * 264 + k0 + quad * 8];
#pragma unroll
    for (int nt = 0; nt < 4; nt++) {
      bf16x8 bv = *(const bf16x8*)&Vt[(nt * 16 + l16) * 264 + k0 + quad * 8];
      o[nt] = MFMA16(ap, bv, o[nt]);
    }
  }

  size_t orow = (size_t)b * 4096 + qt * 64 + wave * 16 + quad * 4;
#pragma unroll
  for (int nt = 0; nt < 4; nt++) {
    int col = h * 64 + nt * 16 + l16;
#pragma unroll
    for (int r = 0; r < 4; r++) O[(orow + r) * 256 + col] = (bf16)o[nt][r];
  }
}

// ---------------- launch ----------------
extern "C" void kernel_launch(void* const* d_in, const int* in_sizes, int n_in,
                              void* d_out, int out_size, void* d_ws, size_t ws_size,
                              hipStream_t stream) {
  (void)in_sizes; (void)n_in; (void)out_size; (void)ws_size;
  const float* x   = (const float*)d_in[0];
  const float* Wq  = (const float*)d_in[3];
  const float* Wkv = (const float*)d_in[4];
  const float* srw = (const float*)d_in[5];
  const float* srb = (const float*)d_in[6];
  const float* lng = (const float*)d_in[7];
  const float* lnb = (const float*)d_in[8];
  const float* Wo  = (const float*)d_in[9];
  const float* bo  = (const float*)d_in[10];
  float* out = (float*)d_out;

  char* ws = (char*)d_ws;
  bf16*  x_bf  = (bf16*)(ws + 0);          // 16,777,216 B
  bf16*  Qbuf  = (bf16*)(ws + 16777216);   // 16,777,216
  bf16*  AObuf = (bf16*)(ws + 33554432);   // 16,777,216
  bf16*  WqT   = (bf16*)(ws + 50331648);   //    131,072
  bf16*  WkvT  = (bf16*)(ws + 50462720);   //    262,144
  bf16*  WoT   = (bf16*)(ws + 50724864);   //    131,072
  bf16*  srwT  = (bf16*)(ws + 50855936);   //  2,097,152
  float* convo = (float*)(ws + 52953088);  //  2,097,152
  bf16*  xln   = (bf16*)(ws + 55050240);   //  1,048,576
  bf16*  kvbuf = (bf16*)(ws + 56098816);   //  2,097,152 (K then V)

  k_cvt<<<8192, 256, 0, stream>>>(x, x_bf);
  k_tr256<<<256, 256, 0, stream>>>(Wq, WqT, 256);
  k_tr256<<<512, 256, 0, stream>>>(Wkv, WkvT, 512);
  k_tr256<<<256, 256, 0, stream>>>(Wo, WoT, 256);
  k_srw<<<4096, 256, 0, stream>>>(srw, srwT);

  // Q = x @ Wq  -> bf16 [32768][256]
  k_gemm<0, 0><<<dim3(512, 4), 256, 0, stream>>>(x_bf, WqT, Qbuf, nullptr, 32768, 256, 256);
  // conv (im2col GEMM, K=4096) + sr_b -> fp32 [2048][256]
  k_gemm<1, 1><<<dim3(32, 4), 256, 0, stream>>>(x_bf, srwT, convo, srb, 2048, 256, 4096);
  // LayerNorm -> bf16 [2048][256]
  k_ln<<<512, 256, 0, stream>>>(convo, lng, lnb, xln);
  // KV = xln @ Wkv -> K/V [32][256][64] bf16
  k_gemm<0, 2><<<dim3(32, 8), 256, 0, stream>>>(xln, WkvT, kvbuf, nullptr, 2048, 512, 256);
  // attention
  k_attn<<<dim3(32, 64), 256, 0, stream>>>(Qbuf, kvbuf, kvbuf + (size_t)32 * 256 * 64, AObuf);
  // out = AO @ Wo + bo -> fp32 d_out
  k_gemm<0, 3><<<dim3(512, 4), 256, 0, stream>>>(AObuf, WoT, out, bo, 32768, 256, 256);
}

// Round 2
// 201.964 us; speedup vs baseline: 1.3814x; 1.3814x over previous
//
#include <hip/hip_runtime.h>

typedef __bf16 bf16;
typedef bf16 bf16x8 __attribute__((ext_vector_type(8)));
typedef bf16 bf16x4 __attribute__((ext_vector_type(4)));
typedef float f32x4 __attribute__((ext_vector_type(4)));

#define MFMA16(a, b, c) __builtin_amdgcn_mfma_f32_16x16x32_bf16(a, b, c, 0, 0, 0)

// ---------------- prep kernels ----------------

// fp32 -> bf16, 4 elements/thread
__global__ void k_cvt(const float* __restrict__ in, bf16* __restrict__ out) {
  int i = (blockIdx.x * 256 + threadIdx.x) * 4;
  float4 v = *(const float4*)(in + i);
  bf16x4 o;
  o[0] = (bf16)v.x; o[1] = (bf16)v.y; o[2] = (bf16)v.z; o[3] = (bf16)v.w;
  *(bf16x4*)(out + i) = o;
}

// transpose fp32 [256][Cc] -> bf16 [Cc][256]
__global__ void k_tr256(const float* __restrict__ in, bf16* __restrict__ out, int Cc) {
  int id = blockIdx.x * 256 + threadIdx.x;   // id = c*256 + r (output-linear)
  int c = id >> 8, r = id & 255;
  out[id] = (bf16)in[r * Cc + c];
}

// sr_w [o][i][p] (p = kh*4+kw, 16) -> srwT [o][p*256 + i]  bf16
__global__ void k_srw(const float* __restrict__ in, bf16* __restrict__ out) {
  int id = blockIdx.x * 256 + threadIdx.x;   // input-linear: o*4096 + i*16 + p
  int o = id >> 12, rem = id & 4095;
  int i = rem >> 4, p = rem & 15;
  out[(o << 12) + (p << 8) + i] = (bf16)in[id];
}

// ---------------- generic MFMA GEMM ----------------
// C[M][N] = A[M][K] @ Bt[N][K]^T   (bf16 inputs, fp32 accum)
// K = K-slice length; blockIdx.z selects slice (z*K .. z*K+K)
// AMODE 0: A row-major [M][K]
// AMODE 1: conv im2col gather from x_bf [B*4096][256]; K index = p*256 + i
// EMODE 0: bf16 store [M][N]
// EMODE 2: KV scatter: K -> [bh][key][d]; V -> transposed [bh][d][key]
// EMODE 3: fp32 store + bias (final output)
// EMODE 4: fp32 partial store at slice blockIdx.z (split-K conv)
template <int AMODE, int EMODE>
__global__ __launch_bounds__(256, 2) void k_gemm(
    const bf16* __restrict__ A, const bf16* __restrict__ Bt,
    void* __restrict__ Cout, const float* __restrict__ bias,
    int M, int N, int K) {
  constexpr int LDT = 72;  // 64 + 8 pad
  __shared__ alignas(16) bf16 As[64 * LDT];
  __shared__ alignas(16) bf16 Bs[64 * LDT];
  int tid = threadIdx.x;
  int m0 = blockIdx.x * 64, n0 = blockIdx.y * 64;
  int kbeg = blockIdx.z * K;
  int wave = tid >> 6, lane = tid & 63;
  int quad = lane >> 4, l16 = lane & 15;

  f32x4 acc[4];
#pragma unroll
  for (int i = 0; i < 4; i++) acc[i] = (f32x4){0.f, 0.f, 0.f, 0.f};

  for (int k0 = kbeg; k0 < kbeg + K; k0 += 64) {
#pragma unroll
    for (int t = 0; t < 2; t++) {
      int c = tid + t * 256;
      int row = c >> 3, c8 = (c & 7) * 8;
      const bf16* asrc;
      if constexpr (AMODE == 0) {
        asrc = A + (size_t)(m0 + row) * K + k0 + c8;
      } else {
        int m = m0 + row;
        int b = m >> 8, tt = m & 255;
        int oh = tt >> 4, ow = tt & 15;
        int p = k0 >> 8;            // patch position (BK=64 never straddles p)
        int kh = p >> 2, kw = p & 3;
        int tok = (oh * 4 + kh) * 64 + ow * 4 + kw;
        asrc = A + ((size_t)(b * 4096 + tok) << 8) + (k0 & 255) + c8;
      }
      *(bf16x8*)&As[row * LDT + c8] = *(const bf16x8*)asrc;
      *(bf16x8*)&Bs[row * LDT + c8] =
          *(const bf16x8*)(Bt + (size_t)(n0 + row) * ((AMODE == 1) ? 4096 : K) + k0 + c8);
    }
    __syncthreads();
#pragma unroll
    for (int kk = 0; kk < 64; kk += 32) {
      bf16x8 af = *(const bf16x8*)&As[(wave * 16 + l16) * LDT + kk + quad * 8];
#pragma unroll
      for (int nt = 0; nt < 4; nt++) {
        bf16x8 bfr = *(const bf16x8*)&Bs[(nt * 16 + l16) * LDT + kk + quad * 8];
        acc[nt] = MFMA16(af, bfr, acc[nt]);
      }
    }
    __syncthreads();
  }

  // epilogue: D[row=quad*4+r][col=l16] per n-tile
  int rbase = m0 + wave * 16 + quad * 4;
#pragma unroll
  for (int nt = 0; nt < 4; nt++) {
    int col = n0 + nt * 16 + l16;
#pragma unroll
    for (int r = 0; r < 4; r++) {
      float v = acc[nt][r];
      int row = rbase + r;
      if constexpr (EMODE == 0) {
        ((bf16*)Cout)[(size_t)row * N + col] = (bf16)v;
      } else if constexpr (EMODE == 2) {
        int b = row >> 8, key = row & 255;
        int isv = col >> 8, c2 = col & 255;
        int hh = c2 >> 6, d = c2 & 63;
        int bh = b * 4 + hh;
        bf16* dst = (bf16*)Cout;
        if (isv == 0)
          dst[(((size_t)bh) * 256 + key) * 64 + d] = (bf16)v;           // K [bh][key][d]
        else
          dst[32 * 256 * 64 + (((size_t)bh) * 64 + d) * 256 + key] = (bf16)v;  // V^T [bh][d][key]
      } else if constexpr (EMODE == 3) {
        ((float*)Cout)[(size_t)row * N + col] = v + bias[col];
      } else {  // EMODE 4
        ((float*)Cout)[((size_t)blockIdx.z * M + row) * N + col] = v;
      }
    }
  }
}

// ---------------- LayerNorm (sum of 8 fp32 partials + sr_b -> bf16) ----------------
__global__ void k_ln(const float* __restrict__ part, const float* __restrict__ srb,
                     const float* __restrict__ g, const float* __restrict__ bb,
                     bf16* __restrict__ out) {
  int row = blockIdx.x * 4 + (threadIdx.x >> 6);
  int lane = threadIdx.x & 63;
  size_t off = (size_t)row * 256 + lane * 4;
  float4 v = *(const float4*)&part[off];
#pragma unroll
  for (int z = 1; z < 8; z++) {
    float4 p = *(const float4*)&part[(size_t)z * 2048 * 256 + off];
    v.x += p.x; v.y += p.y; v.z += p.z; v.w += p.w;
  }
  int c = lane * 4;
  v.x += srb[c + 0]; v.y += srb[c + 1]; v.z += srb[c + 2]; v.w += srb[c + 3];
  float s = v.x + v.y + v.z + v.w;
#pragma unroll
  for (int i = 1; i < 64; i <<= 1) s += __shfl_xor(s, i, 64);
  float mu = s * (1.f / 256.f);
  float d0 = v.x - mu, d1 = v.y - mu, d2 = v.z - mu, d3 = v.w - mu;
  float q = d0 * d0 + d1 * d1 + d2 * d2 + d3 * d3;
#pragma unroll
  for (int i = 1; i < 64; i <<= 1) q += __shfl_xor(q, i, 64);
  float rs = rsqrtf(q * (1.f / 256.f) + 1e-5f);
  bf16x4 o;
  o[0] = (bf16)(d0 * rs * g[c + 0] + bb[c + 0]);
  o[1] = (bf16)(d1 * rs * g[c + 1] + bb[c + 1]);
  o[2] = (bf16)(d2 * rs * g[c + 2] + bb[c + 2]);
  o[3] = (bf16)(d3 * rs * g[c + 3] + bb[c + 3]);
  *(bf16x4*)&out[(size_t)row * 256 + c] = o;
}

// ---------------- attention ----------------
// grid (32 bh, 64 qtiles), block 256 (4 waves); each block: 64 q x 256 keys
__global__ __launch_bounds__(256, 2) void k_attn(
    const bf16* __restrict__ Q,   // [B*4096][256], col = h*64+d
    const bf16* __restrict__ Kb,  // [32][256][64]
    const bf16* __restrict__ Vt_g,// [32][64][256]  (V^T)
    bf16* __restrict__ O) {       // [B*4096][256]
  int bh = blockIdx.x, qt = blockIdx.y;
  int b = bh >> 2, h = bh & 3;
  int tid = threadIdx.x, wave = tid >> 6, lane = tid & 63;
  int quad = lane >> 4, l16 = lane & 15;

  // Qs[64][72] | Ks[256][72] | Vt[64][264];  Ps[64][264] aliases Qs+Ks
  __shared__ alignas(16) bf16 smem[64 * 72 + 256 * 72 + 64 * 264];
  bf16* Qs = smem;
  bf16* Ks = smem + 64 * 72;
  bf16* Vt = smem + 64 * 72 + 256 * 72;
  bf16* Ps = smem;

  // stage Q tile
#pragma unroll
  for (int t = 0; t < 2; t++) {
    int c = tid + t * 256;
    int row = c >> 3, c8 = (c & 7) * 8;
    *(bf16x8*)&Qs[row * 72 + c8] =
        *(const bf16x8*)&Q[((size_t)(b * 4096 + qt * 64 + row) << 8) + h * 64 + c8];
  }
  // stage K [256][64] -> Ks[256][72]
  const bf16* Kbh = Kb + (size_t)bh * 256 * 64;
#pragma unroll
  for (int t = 0; t < 8; t++) {
    int c = tid + t * 256;
    int row = c >> 3, c8 = (c & 7) * 8;
    *(bf16x8*)&Ks[row * 72 + c8] = *(const bf16x8*)&Kbh[row * 64 + c8];
  }
  // stage V^T [64][256] -> Vt[64][264] (vectorized)
  const bf16* Vbh = Vt_g + (size_t)bh * 64 * 256;
#pragma unroll
  for (int t = 0; t < 8; t++) {
    int c = tid + t * 256;
    int row = c >> 5, c8 = (c & 31) * 8;
    *(bf16x8*)&Vt[row * 264 + c8] = *(const bf16x8*)&Vbh[row * 256 + c8];
  }
  __syncthreads();

  // S = Q K^T : wave handles 16 q-rows x all 256 keys
  f32x4 s[16];
#pragma unroll
  for (int i = 0; i < 16; i++) s[i] = (f32x4){0.f, 0.f, 0.f, 0.f};
  bf16x8 aq0 = *(const bf16x8*)&Qs[(wave * 16 + l16) * 72 + 0 + quad * 8];
  bf16x8 aq1 = *(const bf16x8*)&Qs[(wave * 16 + l16) * 72 + 32 + quad * 8];
#pragma unroll
  for (int nt = 0; nt < 16; nt++) {
    bf16x8 b0 = *(const bf16x8*)&Ks[(nt * 16 + l16) * 72 + 0 + quad * 8];
    bf16x8 b1 = *(const bf16x8*)&Ks[(nt * 16 + l16) * 72 + 32 + quad * 8];
    s[nt] = MFMA16(aq0, b0, s[nt]);
    s[nt] = MFMA16(aq1, b1, s[nt]);
  }

  // softmax over 256 keys; lane holds rows quad*4+r, col l16 of each 16-tile
  const float scale = 0.125f;
#pragma unroll
  for (int r = 0; r < 4; r++) {
    float m = -1e30f;
#pragma unroll
    for (int nt = 0; nt < 16; nt++) m = fmaxf(m, s[nt][r]);
#pragma unroll
    for (int i = 1; i < 16; i <<= 1) m = fmaxf(m, __shfl_xor(m, i, 64));
    float sum = 0.f;
#pragma unroll
    for (int nt = 0; nt < 16; nt++) {
      float e = __expf((s[nt][r] - m) * scale);
      s[nt][r] = e;
      sum += e;
    }
#pragma unroll
    for (int i = 1; i < 16; i <<= 1) sum += __shfl_xor(sum, i, 64);
    float inv = 1.f / sum;
#pragma unroll
    for (int nt = 0; nt < 16; nt++) s[nt][r] *= inv;
  }

  __syncthreads();  // done reading Qs/Ks; Ps aliases them
  // write P (C-layout -> LDS row-major)
#pragma unroll
  for (int nt = 0; nt < 16; nt++)
#pragma unroll
    for (int r = 0; r < 4; r++)
      Ps[(wave * 16 + quad * 4 + r) * 264 + nt * 16 + l16] = (bf16)s[nt][r];
  __syncthreads();

  // O = P V : A = Ps [64 q][256 key], Bt = Vt [64 d][256 key]
  f32x4 o[4];
#pragma unroll
  for (int i = 0; i < 4; i++) o[i] = (f32x4){0.f, 0.f, 0.f, 0.f};
#pragma unroll
  for (int k0 = 0; k0 < 256; k0 += 32) {
    bf16x8 ap = *(const bf16x8*)&Ps[(wave * 16 + l16) * 264 + k0 + quad * 8];
#pragma unroll
    for (int nt = 0; nt < 4; nt++) {
      bf16x8 bv = *(const bf16x8*)&Vt[(nt * 16 + l16) * 264 + k0 + quad * 8];
      o[nt] = MFMA16(ap, bv, o[nt]);
    }
  }

  size_t orow = (size_t)b * 4096 + qt * 64 + wave * 16 + quad * 4;
#pragma unroll
  for (int nt = 0; nt < 4; nt++) {
    int col = h * 64 + nt * 16 + l16;
#pragma unroll
    for (int r = 0; r < 4; r++) O[(orow + r) * 256 + col] = (bf16)o[nt][r];
  }
}

// ---------------- launch ----------------
extern "C" void kernel_launch(void* const* d_in, const int* in_sizes, int n_in,
                              void* d_out, int out_size, void* d_ws, size_t ws_size,
                              hipStream_t stream) {
  (void)in_sizes; (void)n_in; (void)out_size; (void)ws_size;
  const float* x   = (const float*)d_in[0];
  const float* Wq  = (const float*)d_in[3];
  const float* Wkv = (const float*)d_in[4];
  const float* srw = (const float*)d_in[5];
  const float* srb = (const float*)d_in[6];
  const float* lng = (const float*)d_in[7];
  const float* lnb = (const float*)d_in[8];
  const float* Wo  = (const float*)d_in[9];
  const float* bo  = (const float*)d_in[10];
  float* out = (float*)d_out;

  char* ws = (char*)d_ws;
  bf16*  x_bf  = (bf16*)(ws + 0);          // 16,777,216 B
  bf16*  Qbuf  = (bf16*)(ws + 16777216);   // 16,777,216
  bf16*  AObuf = (bf16*)(ws + 33554432);   // 16,777,216
  float* convp = (float*)(ws + 33554432);  // 16,777,216 (8 partials; dead before AObuf written)
  bf16*  WqT   = (bf16*)(ws + 50331648);   //    131,072
  bf16*  WkvT  = (bf16*)(ws + 50462720);   //    262,144
  bf16*  WoT   = (bf16*)(ws + 50724864);   //    131,072
  bf16*  srwT  = (bf16*)(ws + 50855936);   //  2,097,152
  bf16*  xln   = (bf16*)(ws + 55050240);   //  1,048,576
  bf16*  kvbuf = (bf16*)(ws + 56098816);   //  2,097,152 (K then V^T)

  k_cvt<<<8192, 256, 0, stream>>>(x, x_bf);
  k_tr256<<<256, 256, 0, stream>>>(Wq, WqT, 256);
  k_tr256<<<512, 256, 0, stream>>>(Wkv, WkvT, 512);
  k_tr256<<<256, 256, 0, stream>>>(Wo, WoT, 256);
  k_srw<<<4096, 256, 0, stream>>>(srw, srwT);

  // Q = x @ Wq  -> bf16 [32768][256]
  k_gemm<0, 0><<<dim3(512, 4), 256, 0, stream>>>(x_bf, WqT, Qbuf, nullptr, 32768, 256, 256);
  // conv (im2col GEMM), split-K 8x512 -> fp32 partials [8][2048][256]
  k_gemm<1, 4><<<dim3(32, 4, 8), 256, 0, stream>>>(x_bf, srwT, convp, nullptr, 2048, 256, 512);
  // LayerNorm (+partial reduce +sr_b) -> bf16 [2048][256]
  k_ln<<<512, 256, 0, stream>>>(convp, srb, lng, lnb, xln);
  // KV = xln @ Wkv -> K [32][256][64], V^T [32][64][256] bf16
  k_gemm<0, 2><<<dim3(32, 8), 256, 0, stream>>>(xln, WkvT, kvbuf, nullptr, 2048, 512, 256);
  // attention
  k_attn<<<dim3(32, 64), 256, 0, stream>>>(Qbuf, kvbuf, kvbuf + (size_t)32 * 256 * 64, AObuf);
  // out = AO @ Wo + bo -> fp32 d_out
  k_gemm<0, 3><<<dim3(512, 4), 256, 0, stream>>>(AObuf, WoT, out, bo, 32768, 256, 256);
}

// Round 3
// 186.818 us; speedup vs baseline: 1.4934x; 1.0811x over previous
//
#include <hip/hip_runtime.h>

typedef __bf16 bf16;
typedef bf16 bf16x8 __attribute__((ext_vector_type(8)));
typedef bf16 bf16x4 __attribute__((ext_vector_type(4)));
typedef float f32x4 __attribute__((ext_vector_type(4)));

#define MFMA16(a, b, c) __builtin_amdgcn_mfma_f32_16x16x32_bf16(a, b, c, 0, 0, 0)

// ---------------- merged prep kernel ----------------
// blocks [0,8192):      x fp32 -> bf16 (4 el/thread)
// blocks [8192,9216):   W transposes (Wq | Wkv | Wo) fp32[r][c] -> bf16[c][r]
// blocks [9216,10240):  sr_w [o][i][p] -> srwT [o][p*256+i] (4 el/thread)
__global__ void k_prep(const float* __restrict__ x, const float* __restrict__ Wq,
                       const float* __restrict__ Wkv, const float* __restrict__ Wo,
                       const float* __restrict__ srw,
                       bf16* __restrict__ x_bf, bf16* __restrict__ WqT,
                       bf16* __restrict__ WkvT, bf16* __restrict__ WoT,
                       bf16* __restrict__ srwT) {
  int bid = blockIdx.x, tid = threadIdx.x;
  if (bid < 8192) {
    int i = (bid * 256 + tid) * 4;
    float4 v = *(const float4*)(x + i);
    bf16x4 o;
    o[0] = (bf16)v.x; o[1] = (bf16)v.y; o[2] = (bf16)v.z; o[3] = (bf16)v.w;
    *(bf16x4*)(x_bf + i) = o;
  } else if (bid < 9216) {
    int id = (bid - 8192) * 256 + tid;  // 0..262143
    if (id < 65536) {                   // WqT
      int c = id >> 8, r = id & 255;
      WqT[id] = (bf16)Wq[r * 256 + c];
    } else if (id < 196608) {           // WkvT
      int l = id - 65536;
      int c = l >> 8, r = l & 255;      // c in 0..511
      WkvT[l] = (bf16)Wkv[r * 512 + c];
    } else {                            // WoT
      int l = id - 196608;
      int c = l >> 8, r = l & 255;
      WoT[l] = (bf16)Wo[r * 256 + c];
    }
  } else {
    int id4 = ((bid - 9216) * 256 + tid) * 4;  // input-linear o*4096+i*16+p
    int o = id4 >> 12, rem = id4 & 4095;
    int i = rem >> 4, p = rem & 15;            // p in {0,4,8,12}
    float4 v = *(const float4*)(srw + id4);
    srwT[(o << 12) + ((p + 0) << 8) + i] = (bf16)v.x;
    srwT[(o << 12) + ((p + 1) << 8) + i] = (bf16)v.y;
    srwT[(o << 12) + ((p + 2) << 8) + i] = (bf16)v.z;
    srwT[(o << 12) + ((p + 3) << 8) + i] = (bf16)v.w;
  }
}

// ---------------- generic MFMA GEMM ----------------
// C[M][N] = A[M][K] @ Bt[N][K]^T   (bf16 inputs, fp32 accum)
// AMODE 0: A row-major [M][K]
// AMODE 1: conv im2col gather from x_bf [B*4096][256]; K index = p*256 + i
// EMODE 2: KV scatter: K -> [bh][key][d]; V -> transposed [bh][d][key]
// EMODE 3: fp32 store + bias (final output)
// EMODE 4: fp32 partial store at slice blockIdx.z (split-K conv)
template <int AMODE, int EMODE>
__global__ __launch_bounds__(256, 2) void k_gemm(
    const bf16* __restrict__ A, const bf16* __restrict__ Bt,
    void* __restrict__ Cout, const float* __restrict__ bias,
    int M, int N, int K) {
  constexpr int LDT = 72;  // 64 + 8 pad
  __shared__ alignas(16) bf16 As[64 * LDT];
  __shared__ alignas(16) bf16 Bs[64 * LDT];
  int tid = threadIdx.x;
  int m0 = blockIdx.x * 64, n0 = blockIdx.y * 64;
  int kbeg = blockIdx.z * K;
  int wave = tid >> 6, lane = tid & 63;
  int quad = lane >> 4, l16 = lane & 15;

  f32x4 acc[4];
#pragma unroll
  for (int i = 0; i < 4; i++) acc[i] = (f32x4){0.f, 0.f, 0.f, 0.f};

  for (int k0 = kbeg; k0 < kbeg + K; k0 += 64) {
#pragma unroll
    for (int t = 0; t < 2; t++) {
      int c = tid + t * 256;
      int row = c >> 3, c8 = (c & 7) * 8;
      const bf16* asrc;
      if constexpr (AMODE == 0) {
        asrc = A + (size_t)(m0 + row) * K + k0 + c8;
      } else {
        int m = m0 + row;
        int b = m >> 8, tt = m & 255;
        int oh = tt >> 4, ow = tt & 15;
        int p = k0 >> 8;            // patch position (BK=64 never straddles p)
        int kh = p >> 2, kw = p & 3;
        int tok = (oh * 4 + kh) * 64 + ow * 4 + kw;
        asrc = A + ((size_t)(b * 4096 + tok) << 8) + (k0 & 255) + c8;
      }
      *(bf16x8*)&As[row * LDT + c8] = *(const bf16x8*)asrc;
      *(bf16x8*)&Bs[row * LDT + c8] =
          *(const bf16x8*)(Bt + (size_t)(n0 + row) * ((AMODE == 1) ? 4096 : K) + k0 + c8);
    }
    __syncthreads();
#pragma unroll
    for (int kk = 0; kk < 64; kk += 32) {
      bf16x8 af = *(const bf16x8*)&As[(wave * 16 + l16) * LDT + kk + quad * 8];
#pragma unroll
      for (int nt = 0; nt < 4; nt++) {
        bf16x8 bfr = *(const bf16x8*)&Bs[(nt * 16 + l16) * LDT + kk + quad * 8];
        acc[nt] = MFMA16(af, bfr, acc[nt]);
      }
    }
    __syncthreads();
  }

  int rbase = m0 + wave * 16 + quad * 4;
#pragma unroll
  for (int nt = 0; nt < 4; nt++) {
    int col = n0 + nt * 16 + l16;
#pragma unroll
    for (int r = 0; r < 4; r++) {
      float v = acc[nt][r];
      int row = rbase + r;
      if constexpr (EMODE == 2) {
        int b = row >> 8, key = row & 255;
        int isv = col >> 8, c2 = col & 255;
        int hh = c2 >> 6, d = c2 & 63;
        int bh = b * 4 + hh;
        bf16* dst = (bf16*)Cout;
        if (isv == 0)
          dst[(((size_t)bh) * 256 + key) * 64 + d] = (bf16)v;                  // K [bh][key][d]
        else
          dst[32 * 256 * 64 + (((size_t)bh) * 64 + d) * 256 + key] = (bf16)v;  // V^T [bh][d][key]
      } else if constexpr (EMODE == 3) {
        ((float*)Cout)[(size_t)row * N + col] = v + bias[col];
      } else {  // EMODE 4
        ((float*)Cout)[((size_t)blockIdx.z * M + row) * N + col] = v;
      }
    }
  }
}

// ---------------- LayerNorm (sum of 8 fp32 partials + sr_b -> bf16) ----------------
__global__ void k_ln(const float* __restrict__ part, const float* __restrict__ srb,
                     const float* __restrict__ g, const float* __restrict__ bb,
                     bf16* __restrict__ out) {
  int row = blockIdx.x * 4 + (threadIdx.x >> 6);
  int lane = threadIdx.x & 63;
  size_t off = (size_t)row * 256 + lane * 4;
  float4 v = *(const float4*)&part[off];
#pragma unroll
  for (int z = 1; z < 8; z++) {
    float4 p = *(const float4*)&part[(size_t)z * 2048 * 256 + off];
    v.x += p.x; v.y += p.y; v.z += p.z; v.w += p.w;
  }
  int c = lane * 4;
  v.x += srb[c + 0]; v.y += srb[c + 1]; v.z += srb[c + 2]; v.w += srb[c + 3];
  float s = v.x + v.y + v.z + v.w;
#pragma unroll
  for (int i = 1; i < 64; i <<= 1) s += __shfl_xor(s, i, 64);
  float mu = s * (1.f / 256.f);
  float d0 = v.x - mu, d1 = v.y - mu, d2 = v.z - mu, d3 = v.w - mu;
  float q = d0 * d0 + d1 * d1 + d2 * d2 + d3 * d3;
#pragma unroll
  for (int i = 1; i < 64; i <<= 1) q += __shfl_xor(q, i, 64);
  float rs = rsqrtf(q * (1.f / 256.f) + 1e-5f);
  bf16x4 o;
  o[0] = (bf16)(d0 * rs * g[c + 0] + bb[c + 0]);
  o[1] = (bf16)(d1 * rs * g[c + 1] + bb[c + 1]);
  o[2] = (bf16)(d2 * rs * g[c + 2] + bb[c + 2]);
  o[3] = (bf16)(d3 * rs * g[c + 3] + bb[c + 3]);
  *(bf16x4*)&out[(size_t)row * 256 + c] = o;
}

// ---------------- attention with fused Q-projection ----------------
// grid (32 bh, 64 qtiles), block 256 (4 waves)
// phase 1: Q = x_tile @ Wq[head]  (x, Wq staged in LDS; Q -> Qs via C->A layout)
// phase 2: S = Q K^T, softmax, O = P V
__global__ __launch_bounds__(256, 2) void k_attn(
    const bf16* __restrict__ xbf,  // [B*4096][256]
    const bf16* __restrict__ WqT,  // [256 out][256 in]
    const bf16* __restrict__ Kb,   // [32][256][64]
    const bf16* __restrict__ Vt_g, // [32][64][256]  (V^T)
    bf16* __restrict__ O) {        // [B*4096][256]
  int bh = blockIdx.x, qt = blockIdx.y;
  int b = bh >> 2, h = bh & 3;
  int tid = threadIdx.x, wave = tid >> 6, lane = tid & 63;
  int quad = lane >> 4, l16 = lane & 15;

  // R1 (36864B): Xs[64][264] / Ks[256][72] / Ps[64][264]
  // R2 (33792B): Ws[64][264] / Vt[64][264]
  // Qs (9216B):  Qs[64][72]
  __shared__ alignas(16) bf16 smem[39936];
  bf16* R1 = smem;
  bf16* R2 = smem + 18432;
  bf16* Qs = smem + 35328;

  // ---- phase 1: stage x tile + Wq head slice ----
#pragma unroll
  for (int t = 0; t < 8; t++) {
    int c = tid + t * 256;
    int row = c >> 5, c8 = (c & 31) * 8;
    *(bf16x8*)&R1[row * 264 + c8] =
        *(const bf16x8*)&xbf[((size_t)(b * 4096 + qt * 64 + row) << 8) + c8];
    *(bf16x8*)&R2[row * 264 + c8] =
        *(const bf16x8*)&WqT[((size_t)(h * 64 + row) << 8) + c8];
  }
  __syncthreads();

  f32x4 q[4];
#pragma unroll
  for (int i = 0; i < 4; i++) q[i] = (f32x4){0.f, 0.f, 0.f, 0.f};
#pragma unroll
  for (int k0 = 0; k0 < 256; k0 += 32) {
    bf16x8 ax = *(const bf16x8*)&R1[(wave * 16 + l16) * 264 + k0 + quad * 8];
#pragma unroll
    for (int nt = 0; nt < 4; nt++) {
      bf16x8 bw = *(const bf16x8*)&R2[(nt * 16 + l16) * 264 + k0 + quad * 8];
      q[nt] = MFMA16(ax, bw, q[nt]);
    }
  }
  __syncthreads();  // all reads of R1/R2 done; safe to overwrite

  // write Q (C-layout -> Qs row-major [q][d])
#pragma unroll
  for (int nt = 0; nt < 4; nt++)
#pragma unroll
    for (int r = 0; r < 4; r++)
      Qs[(wave * 16 + quad * 4 + r) * 72 + nt * 16 + l16] = (bf16)q[nt][r];

  // stage K [256][64] -> R1 Ks[256][72]
  const bf16* Kbh = Kb + (size_t)bh * 256 * 64;
#pragma unroll
  for (int t = 0; t < 8; t++) {
    int c = tid + t * 256;
    int row = c >> 3, c8 = (c & 7) * 8;
    *(bf16x8*)&R1[row * 72 + c8] = *(const bf16x8*)&Kbh[row * 64 + c8];
  }
  // stage V^T [64][256] -> R2 Vt[64][264]
  const bf16* Vbh = Vt_g + (size_t)bh * 64 * 256;
#pragma unroll
  for (int t = 0; t < 8; t++) {
    int c = tid + t * 256;
    int row = c >> 5, c8 = (c & 31) * 8;
    *(bf16x8*)&R2[row * 264 + c8] = *(const bf16x8*)&Vbh[row * 256 + c8];
  }
  __syncthreads();

  // ---- phase 2: S = Q K^T ----
  f32x4 s[16];
#pragma unroll
  for (int i = 0; i < 16; i++) s[i] = (f32x4){0.f, 0.f, 0.f, 0.f};
  bf16x8 aq0 = *(const bf16x8*)&Qs[(wave * 16 + l16) * 72 + 0 + quad * 8];
  bf16x8 aq1 = *(const bf16x8*)&Qs[(wave * 16 + l16) * 72 + 32 + quad * 8];
#pragma unroll
  for (int nt = 0; nt < 16; nt++) {
    bf16x8 b0 = *(const bf16x8*)&R1[(nt * 16 + l16) * 72 + 0 + quad * 8];
    bf16x8 b1 = *(const bf16x8*)&R1[(nt * 16 + l16) * 72 + 32 + quad * 8];
    s[nt] = MFMA16(aq0, b0, s[nt]);
    s[nt] = MFMA16(aq1, b1, s[nt]);
  }

  // softmax over 256 keys
  const float scale = 0.125f;
#pragma unroll
  for (int r = 0; r < 4; r++) {
    float m = -1e30f;
#pragma unroll
    for (int nt = 0; nt < 16; nt++) m = fmaxf(m, s[nt][r]);
#pragma unroll
    for (int i = 1; i < 16; i <<= 1) m = fmaxf(m, __shfl_xor(m, i, 64));
    float sum = 0.f;
#pragma unroll
    for (int nt = 0; nt < 16; nt++) {
      float e = __expf((s[nt][r] - m) * scale);
      s[nt][r] = e;
      sum += e;
    }
#pragma unroll
    for (int i = 1; i < 16; i <<= 1) sum += __shfl_xor(sum, i, 64);
    float inv = 1.f / sum;
#pragma unroll
    for (int nt = 0; nt < 16; nt++) s[nt][r] *= inv;
  }

  __syncthreads();  // done reading Ks; Ps aliases R1
#pragma unroll
  for (int nt = 0; nt < 16; nt++)
#pragma unroll
    for (int r = 0; r < 4; r++)
      R1[(wave * 16 + quad * 4 + r) * 264 + nt * 16 + l16] = (bf16)s[nt][r];
  __syncthreads();

  // O = P V : A = Ps [64 q][256 key], Bt = Vt [64 d][256 key]
  f32x4 o[4];
#pragma unroll
  for (int i = 0; i < 4; i++) o[i] = (f32x4){0.f, 0.f, 0.f, 0.f};
#pragma unroll
  for (int k0 = 0; k0 < 256; k0 += 32) {
    bf16x8 ap = *(const bf16x8*)&R1[(wave * 16 + l16) * 264 + k0 + quad * 8];
#pragma unroll
    for (int nt = 0; nt < 4; nt++) {
      bf16x8 bv = *(const bf16x8*)&R2[(nt * 16 + l16) * 264 + k0 + quad * 8];
      o[nt] = MFMA16(ap, bv, o[nt]);
    }
  }

  size_t orow = (size_t)b * 4096 + qt * 64 + wave * 16 + quad * 4;
#pragma unroll
  for (int nt = 0; nt < 4; nt++) {
    int col = h * 64 + nt * 16 + l16;
#pragma unroll
    for (int r = 0; r < 4; r++) O[(orow + r) * 256 + col] = (bf16)o[nt][r];
  }
}

// ---------------- launch ----------------
extern "C" void kernel_launch(void* const* d_in, const int* in_sizes, int n_in,
                              void* d_out, int out_size, void* d_ws, size_t ws_size,
                              hipStream_t stream) {
  (void)in_sizes; (void)n_in; (void)out_size; (void)ws_size;
  const float* x   = (const float*)d_in[0];
  const float* Wq  = (const float*)d_in[3];
  const float* Wkv = (const float*)d_in[4];
  const float* srw = (const float*)d_in[5];
  const float* srb = (const float*)d_in[6];
  const float* lng = (const float*)d_in[7];
  const float* lnb = (const float*)d_in[8];
  const float* Wo  = (const float*)d_in[9];
  const float* bo  = (const float*)d_in[10];
  float* out = (float*)d_out;

  char* ws = (char*)d_ws;
  bf16*  x_bf  = (bf16*)(ws + 0);          // 16,777,216 B
  bf16*  AObuf = (bf16*)(ws + 16777216);   // 16,777,216
  float* convp = (float*)(ws + 33554432);  // 16,777,216 (8 partials)
  bf16*  WqT   = (bf16*)(ws + 50331648);   //    131,072
  bf16*  WkvT  = (bf16*)(ws + 50462720);   //    262,144
  bf16*  WoT   = (bf16*)(ws + 50724864);   //    131,072
  bf16*  srwT  = (bf16*)(ws + 50855936);   //  2,097,152
  bf16*  xln   = (bf16*)(ws + 52953088);   //  1,048,576
  bf16*  kvbuf = (bf16*)(ws + 54001664);   //  2,097,152 (K then V^T)

  k_prep<<<10240, 256, 0, stream>>>(x, Wq, Wkv, Wo, srw, x_bf, WqT, WkvT, WoT, srwT);
  // conv (im2col GEMM), split-K 8x512 -> fp32 partials [8][2048][256]
  k_gemm<1, 4><<<dim3(32, 4, 8), 256, 0, stream>>>(x_bf, srwT, convp, nullptr, 2048, 256, 512);
  // LayerNorm (+partial reduce +sr_b) -> bf16 [2048][256]
  k_ln<<<512, 256, 0, stream>>>(convp, srb, lng, lnb, xln);
  // KV = xln @ Wkv -> K [32][256][64], V^T [32][64][256] bf16
  k_gemm<0, 2><<<dim3(32, 8), 256, 0, stream>>>(xln, WkvT, kvbuf, nullptr, 2048, 512, 256);
  // attention (Q-proj fused)
  k_attn<<<dim3(32, 64), 256, 0, stream>>>(x_bf, WqT, kvbuf, kvbuf + (size_t)32 * 256 * 64, AObuf);
  // out = AO @ Wo + bo -> fp32 d_out
  k_gemm<0, 3><<<dim3(512, 4), 256, 0, stream>>>(AObuf, WoT, out, bo, 32768, 256, 256);
}